// Round 1
// 181.483 us; speedup vs baseline: 1.0020x; 1.0020x over previous
//
#include <hip/hip_runtime.h>

// Word embedding gather: out[token, :] = weight[ids[token], :]
// ids: (8192,) int32 ; weight: (32000, 1024) fp32 ; out: (8192, 1024) fp32
//
// Restructured for memory-level parallelism: 8 tokens per 256-thread block
// (1024 blocks). Each thread owns one float4 column slot and copies it for
// all 8 tokens:
//   1. 8 wave-uniform id loads issued up front (independent, scalarizable)
//   2. 8 independent 16B gather loads in flight per lane (ILP=8 vs ILP=1
//      in the 1-token-per-block version -> 8x in-flight cache lines/wave)
//   3. stores drain pipelined (compiler emits vmcnt(7)..vmcnt(0))
// Stores are non-temporal: the 33.5 MB output is write-once; keep L2/LLC
// for the 131 MB weight table (which fully fits in the 256 MiB L3).

typedef float floatx4 __attribute__((ext_vector_type(4)));

#define DIM4 256  // 1024 floats / 4 per float4
#define TOK  8    // tokens per block

__global__ __launch_bounds__(256) void embed_gather_kernel(
    const int* __restrict__ ids,
    const floatx4* __restrict__ weight,
    floatx4* __restrict__ out,
    int n_tokens)
{
    const int t0   = blockIdx.x * TOK;
    const int lane = threadIdx.x;  // 0..255, one float4 column per thread

    // 1) all token ids up front (wave-uniform -> scalar loads, independent)
    int id[TOK];
#pragma unroll
    for (int i = 0; i < TOK; ++i) {
        const int t = t0 + i;
        id[i] = (t < n_tokens) ? ids[t] : 0;
    }

    // 2) 8 independent gather loads in flight
    floatx4 v[TOK];
#pragma unroll
    for (int i = 0; i < TOK; ++i)
        v[i] = weight[(size_t)id[i] * DIM4 + lane];

    // 3) pipelined non-temporal stores (contiguous 1 KiB per wave per store)
    #pragma unroll
    for (int i = 0; i < TOK; ++i) {
        const int t = t0 + i;
        if (t < n_tokens)
            __builtin_nontemporal_store(v[i], &out[(size_t)t * DIM4 + lane]);
    }
}

extern "C" void kernel_launch(void* const* d_in, const int* in_sizes, int n_in,
                              void* d_out, int out_size, void* d_ws, size_t ws_size,
                              hipStream_t stream) {
    const int*     ids    = (const int*)d_in[0];       // input_ids, 8192 int32
    const floatx4* weight = (const floatx4*)d_in[1];   // (32000, 1024) fp32
    floatx4*       out    = (floatx4*)d_out;           // (8192, 1024) fp32

    const int n_tokens = in_sizes[0];                  // 8192
    const int blocks   = (n_tokens + TOK - 1) / TOK;   // 1024

    embed_gather_kernel<<<blocks, DIM4, 0, stream>>>(ids, weight, out, n_tokens);
}

// Round 2
// 175.461 us; speedup vs baseline: 1.0364x; 1.0343x over previous
//
#include <hip/hip_runtime.h>

// Word embedding gather: out[token, :] = weight[ids[token], :]
// ids: (8192,) int32 ; weight: (32000, 1024) fp32 ; out: (8192, 1024) fp32
//
// 8 tokens per 256-thread block (1024 blocks), one float4 column slot per
// thread. Both loads AND stores are non-temporal: the harness poisons
// ~1 GB immediately before this kernel, leaving all 32 MB of L2 dirty.
// Allocating reads/writes would evict dirty fill lines inside our window
// (~32 MB of extra writeback traffic). Non-allocating accesses keep our
// effective traffic at the 67 MB ideal (33.5 MB read + 33.5 MB write).
// Row-reuse via L2 (~12% duplicate ids) is worth less than the eviction
// cost it triggers.

typedef float floatx4 __attribute__((ext_vector_type(4)));

#define DIM4 256  // 1024 floats / 4 per float4
#define TOK  8    // tokens per block

__global__ __launch_bounds__(256) void embed_gather_kernel(
    const int* __restrict__ ids,
    const floatx4* __restrict__ weight,
    floatx4* __restrict__ out,
    int n_tokens)
{
    const int t0   = blockIdx.x * TOK;
    const int lane = threadIdx.x;  // 0..255, one float4 column per thread

    // 1) all token ids up front (block-uniform -> scalar loads, independent)
    int id[TOK];
#pragma unroll
    for (int i = 0; i < TOK; ++i) {
        const int t = t0 + i;
        id[i] = (t < n_tokens) ? ids[t] : 0;
    }

    // 2) 8 independent non-temporal gather loads in flight
    floatx4 v[TOK];
#pragma unroll
    for (int i = 0; i < TOK; ++i)
        v[i] = __builtin_nontemporal_load(&weight[(size_t)id[i] * DIM4 + lane]);

    // 3) pipelined non-temporal stores (contiguous 1 KiB per wave per store)
#pragma unroll
    for (int i = 0; i < TOK; ++i) {
        const int t = t0 + i;
        if (t < n_tokens)
            __builtin_nontemporal_store(v[i], &out[(size_t)t * DIM4 + lane]);
    }
}

extern "C" void kernel_launch(void* const* d_in, const int* in_sizes, int n_in,
                              void* d_out, int out_size, void* d_ws, size_t ws_size,
                              hipStream_t stream) {
    const int*     ids    = (const int*)d_in[0];       // input_ids, 8192 int32
    const floatx4* weight = (const floatx4*)d_in[1];   // (32000, 1024) fp32
    floatx4*       out    = (floatx4*)d_out;           // (8192, 1024) fp32

    const int n_tokens = in_sizes[0];                  // 8192
    const int blocks   = (n_tokens + TOK - 1) / TOK;   // 1024

    embed_gather_kernel<<<blocks, DIM4, 0, stream>>>(ids, weight, out, n_tokens);
}